// Round 4
// baseline (746.021 us; speedup 1.0000x reference)
//
#include <hip/hip_runtime.h>
#include <hip/hip_bf16.h>

// RNN: h_t = tanh(x_t U + h_{t-1} W + b), return h_T.  B=256 T=512 D=K=256.
// Phase 0: transpose U -> Ut fp16 [256][264].
// Phase 1: xu_gemm v2 — LDS-free, barrier-free. Each lane loads A-frags direct
//          from global x (k-contiguous) and B-frags from L2-resident Ut.
//          8192 blocks x 4 waves; wave = 16 rows x 64 cols, 32 MFMAs.
// Phase 2: 16 blocks x 16 batch rows x 4 waves. W stationary in VGPRs; h
//          ping-pongs through XOR-swizzled LDS. KEY: barriers are
//          lgkmcnt-only (inline asm) so xu prefetch (depth 4, registers)
//          stays in flight across steps — no vmcnt(0) drain per step.

typedef _Float16 half8_t __attribute__((ext_vector_type(8)));
typedef _Float16 half2_t __attribute__((ext_vector_type(2)));
typedef float    float4_t __attribute__((ext_vector_type(4)));

#define MFMA16(a, b, c) __builtin_amdgcn_mfma_f32_16x16x32_f16((a), (b), (c), 0, 0, 0)
// LDS-visibility barrier WITHOUT vmcnt drain (xu register loads stay in flight;
// compiler inserts its own vmcnt waits at point-of-use).
#define BARRIER_LGKM() asm volatile("s_waitcnt lgkmcnt(0)\n\ts_barrier" ::: "memory")

__device__ __forceinline__ half2_t pk_h2(float a, float b) {
    auto r = __builtin_amdgcn_cvt_pkrtz(a, b);
    return __builtin_bit_cast(half2_t, r);
}

__device__ __forceinline__ float fast_tanh(float x) {
    float e = __expf(2.0f * x);
    return 1.0f - 2.0f * __builtin_amdgcn_rcpf(e + 1.0f);
}

// ---------------- Phase 0 ----------------
__global__ void transpose_u(const float* __restrict__ U, _Float16* __restrict__ Ut) {
    int id = blockIdx.x * 256 + threadIdx.x;
    int d = id >> 8, n = id & 255;
    Ut[n * 264 + d] = (_Float16)U[id];
}

// ---------------- Phase 1: xu GEMM, LDS-free ----------------
// Block bx: t = bx>>4, b0 = (bx&15)*16. Wave w: cols [64w, 64w+64) as two
// interleaved pairs (s, tt): col = 64w + 32s + 2*l15 + tt.
__global__ __launch_bounds__(256, 2) void xu_gemm(
    const float* __restrict__ x,        // [256][512][256] fp32
    const _Float16* __restrict__ Ut,    // [256][264] fp16
    half2_t* __restrict__ xu)           // [(t*256+b)][128] half2
{
    const int tid = threadIdx.x;
    const int lane = tid & 63, w = tid >> 6, l15 = lane & 15, q = lane >> 4;
    const int bx = blockIdx.x;
    const int t = bx >> 4;
    const int b0 = (bx & 15) * 16;
    const int n0 = 64 * w;

    // B-frags: col n, k = 32c+8q+j  (16B contiguous in Ut row)
    half8_t bf[2][2][8];
#pragma unroll
    for (int s = 0; s < 2; ++s)
#pragma unroll
        for (int tt = 0; tt < 2; ++tt) {
            const char* bp = (const char*)Ut + (size_t)(n0 + 32 * s + 2 * l15 + tt) * 528 + q * 16;
#pragma unroll
            for (int c = 0; c < 8; ++c)
                bf[s][tt][c] = *(const half8_t*)(bp + c * 64);
        }

    // A-frags: row = b0+l15 (A-operand row = l15), k = 32c+8q+j, fp32 -> fp16
    const float* ap = x + ((size_t)(b0 + l15) * 512 + t) * 256 + 8 * q;
    half8_t af[8];
#pragma unroll
    for (int c = 0; c < 8; ++c) {
        float4 a0 = *(const float4*)(ap + 32 * c);
        float4 a1 = *(const float4*)(ap + 32 * c + 4);
        uint4 u;
        u.x = __builtin_bit_cast(unsigned, pk_h2(a0.x, a0.y));
        u.y = __builtin_bit_cast(unsigned, pk_h2(a0.z, a0.w));
        u.z = __builtin_bit_cast(unsigned, pk_h2(a1.x, a1.y));
        u.w = __builtin_bit_cast(unsigned, pk_h2(a1.z, a1.w));
        af[c] = __builtin_bit_cast(half8_t, u);
    }

    float4_t acc[2][2];
#pragma unroll
    for (int s = 0; s < 2; ++s)
#pragma unroll
        for (int tt = 0; tt < 2; ++tt)
#pragma unroll
            for (int i = 0; i < 4; ++i) acc[s][tt][i] = 0.f;

#pragma unroll
    for (int c = 0; c < 8; ++c)
#pragma unroll
        for (int s = 0; s < 2; ++s)
#pragma unroll
            for (int tt = 0; tt < 2; ++tt)
                acc[s][tt] = MFMA16(af[c], bf[s][tt][c], acc[s][tt]);

    // store: C row = 4q+i, col pair (64w+32s+2*l15, +1) -> half2 index 32w+16s+l15
#pragma unroll
    for (int s = 0; s < 2; ++s)
#pragma unroll
        for (int i = 0; i < 4; ++i) {
            half2_t p = pk_h2(acc[s][0][i], acc[s][1][i]);
            xu[(size_t)(t * 256 + b0 + 4 * q + i) * 128 + 32 * w + 16 * s + l15] = p;
        }
}

// ---------------- Phase 2: 512-step scan, 4 waves, swizzled LDS -------------------
__global__ __launch_bounds__(256, 1) void rnn_scan(
    const half2_t* __restrict__ xu,     // [(t*256+b)][128] half2
    const float* __restrict__ W,        // [256][256] fp32
    const float* __restrict__ bias,     // [256]
    float* __restrict__ out)            // [256][256] fp32
{
    __shared__ char lds[16384];         // h dbuf: 2 x (16 rows x 512B), XOR-swizzled
    const int tid = threadIdx.x;
    const int lane = tid & 63, w = tid >> 6, l15 = lane & 15, q = lane >> 4;
    const int blk = blockIdx.x;

    // W -> B-frags: wf[s][tt][c], k = 32c+8q+j, col = 64w+32s+2*l15+tt
    half8_t wf[2][2][8];
#pragma unroll
    for (int s = 0; s < 2; ++s)
#pragma unroll
        for (int tt = 0; tt < 2; ++tt)
#pragma unroll
            for (int c = 0; c < 8; ++c) {
                half8_t f;
#pragma unroll
                for (int j = 0; j < 8; ++j) {
                    int k = 32 * c + q * 8 + j;
                    f[j] = (_Float16)W[k * 256 + 64 * w + 32 * s + 2 * l15 + tt];
                }
                wf[s][tt][c] = f;
            }
    float bs[2][2];
#pragma unroll
    for (int s = 0; s < 2; ++s)
#pragma unroll
        for (int tt = 0; tt < 2; ++tt)
            bs[s][tt] = bias[64 * w + 32 * s + 2 * l15 + tt];

    // h0 = 0
    for (int i = tid; i < 4096; i += 256) ((int*)lds)[i] = 0;

    // step-invariant swizzled LDS addresses (buffer-0 base)
    int raddr[8];
#pragma unroll
    for (int c = 0; c < 8; ++c)
        raddr[c] = l15 * 512 + 16 * ((4 * c + q) ^ (l15 & 7));
    int waddr[2][4];
#pragma unroll
    for (int s = 0; s < 2; ++s)
#pragma unroll
        for (int i = 0; i < 4; ++i) {
            int r = 4 * q + i;
            int g = 8 * w + 4 * s + (l15 >> 2);
            waddr[s][i] = r * 512 + (g ^ (r & 7)) * 16 + (l15 & 3) * 4;
        }

    const int rowg0 = 16 * blk + 4 * q;
    const int cpair0 = 32 * w + l15;    // + 16*s

    auto load_xu = [&](half2_t (&dst)[8], int t) {
#pragma unroll
        for (int s = 0; s < 2; ++s)
#pragma unroll
            for (int i = 0; i < 4; ++i)
                dst[s * 4 + i] = xu[((size_t)t * 256 + rowg0 + i) * 128 + cpair0 + 16 * s];
    };

    half2_t xr0[8], xr1[8], xr2[8], xr3[8];
    load_xu(xr0, 0);
    load_xu(xr1, 1);
    load_xu(xr2, 2);
    load_xu(xr3, 3);
    __syncthreads();   // one-time full drain, fine

    auto step = [&](half2_t (&xreg)[8], int t) {
        float4_t acc[2][2];
#pragma unroll
        for (int s = 0; s < 2; ++s)
#pragma unroll
            for (int tt = 0; tt < 2; ++tt)
#pragma unroll
                for (int i = 0; i < 4; ++i)
                    acc[s][tt][i] = (float)xreg[s * 4 + i][tt];

        int tp = t + 4 > 511 ? 511 : t + 4;     // depth-4 prefetch
        load_xu(xreg, tp);

        const char* base = lds + (t & 1) * 8192;
        half8_t af[8];
#pragma unroll
        for (int c = 0; c < 8; ++c)
            af[c] = *(const half8_t*)(base + raddr[c]);

#pragma unroll
        for (int c = 0; c < 8; ++c)
#pragma unroll
            for (int s = 0; s < 2; ++s)
#pragma unroll
                for (int tt = 0; tt < 2; ++tt)
                    acc[s][tt] = MFMA16(af[c], wf[s][tt][c], acc[s][tt]);

        if (t == 511) {
#pragma unroll
            for (int s = 0; s < 2; ++s)
#pragma unroll
                for (int i = 0; i < 4; ++i) {
                    float v0 = fast_tanh(acc[s][0][i] + bs[s][0]);
                    float v1 = fast_tanh(acc[s][1][i] + bs[s][1]);
                    float2 st; st.x = v0; st.y = v1;
                    *(float2*)(&out[(rowg0 + i) * 256 + 64 * w + 32 * s + 2 * l15]) = st;
                }
        } else {
            char* nb = lds + ((t + 1) & 1) * 8192;
#pragma unroll
            for (int s = 0; s < 2; ++s)
#pragma unroll
                for (int i = 0; i < 4; ++i) {
                    float v0 = fast_tanh(acc[s][0][i] + bs[s][0]);
                    float v1 = fast_tanh(acc[s][1][i] + bs[s][1]);
                    *(half2_t*)(nb + waddr[s][i]) = pk_h2(v0, v1);
                }
            BARRIER_LGKM();   // LDS-only sync; xu loads stay in flight
        }
    };

    for (int t4 = 0; t4 < 512; t4 += 4) {
        step(xr0, t4);
        step(xr1, t4 + 1);
        step(xr2, t4 + 2);
        step(xr3, t4 + 3);
    }
}

extern "C" void kernel_launch(void* const* d_in, const int* in_sizes, int n_in,
                              void* d_out, int out_size, void* d_ws, size_t ws_size,
                              hipStream_t stream) {
    const float* x = (const float*)d_in[0];   // [256,512,256]
    const float* U = (const float*)d_in[1];   // [256,256]
    const float* W = (const float*)d_in[2];   // [256,256]
    const float* b = (const float*)d_in[3];   // [256]
    float* out = (float*)d_out;

    char* ws = (char*)d_ws;
    _Float16* Ut = (_Float16*)ws;                       // 135168 B
    half2_t*  xu = (half2_t*)(ws + 262144);             // 67,108,864 B

    transpose_u<<<256, 256, 0, stream>>>(U, Ut);
    xu_gemm<<<8192, 256, 0, stream>>>(x, Ut, xu);
    rnn_scan<<<16, 256, 0, stream>>>(xu, W, b, out);
}

// Round 5
// 627.925 us; speedup vs baseline: 1.1881x; 1.1881x over previous
//
#include <hip/hip_runtime.h>
#include <hip/hip_bf16.h>

// RNN: h_t = tanh(x_t U + h_{t-1} W + b), return h_T.  B=256 T=512 D=K=256.
// Phase 0: transpose U -> Ut fp16 [256][264].
// Phase 1: xu_gemm v3 — barrier-free, LDS-free. Block = 32 t-rows (contiguous
//          32KB x window at fixed b) x 128 cols; 4 waves = 2 rowg x 2 colg.
//          B (Ut) K=256 entirely in VGPRs; x read <=2x (col-halves, L3 absorbs).
// Phase 2: scan, R2-proven 8-wave config (2 waves/SIMD latency hiding) +
//          lgkm-only barrier (xu HBM prefetch stays in flight across steps) +
//          depth-2 register prefetch.

typedef _Float16 half8_t __attribute__((ext_vector_type(8)));
typedef _Float16 half2_t __attribute__((ext_vector_type(2)));
typedef float    float4_t __attribute__((ext_vector_type(4)));

#define MFMA16(a, b, c) __builtin_amdgcn_mfma_f32_16x16x32_f16((a), (b), (c), 0, 0, 0)
// LDS-visibility barrier WITHOUT the vmcnt(0) drain __syncthreads implies.
#define BARRIER_LGKM() asm volatile("s_waitcnt lgkmcnt(0)\n\ts_barrier" ::: "memory")

__device__ __forceinline__ half2_t pk_h2(float a, float b) {
    auto r = __builtin_amdgcn_cvt_pkrtz(a, b);
    return __builtin_bit_cast(half2_t, r);
}

__device__ __forceinline__ float fast_tanh(float x) {
    float e = __expf(2.0f * x);
    return 1.0f - 2.0f * __builtin_amdgcn_rcpf(e + 1.0f);
}

// ---------------- Phase 0 ----------------
__global__ void transpose_u(const float* __restrict__ U, _Float16* __restrict__ Ut) {
    int id = blockIdx.x * 256 + threadIdx.x;
    int d = id >> 8, n = id & 255;
    Ut[n * 264 + d] = (_Float16)U[id];
}

// ---------------- Phase 1: xu GEMM v3 ----------------
// bx = (b<<5) | (tc<<1) | ch.  Block: rows m = t*256+b for t in [32tc,32tc+32),
// cols [128ch, 128ch+128). Wave w: rowg=w&1 (16 t), colg=w>>1 (64 cols).
__global__ __launch_bounds__(256, 2) void xu_gemm(
    const float* __restrict__ x,        // [256][512][256] fp32
    const _Float16* __restrict__ Ut,    // [256][264] fp16
    half2_t* __restrict__ xu)           // [(t*256+b)][128] half2
{
    const int tid = threadIdx.x;
    const int lane = tid & 63, w = tid >> 6, l15 = lane & 15, q = lane >> 4;
    const int bx = blockIdx.x;
    const int b = bx >> 5;
    const int t0 = ((bx >> 1) & 15) * 32;
    const int ch = bx & 1;
    const int rowg = w & 1, colg = w >> 1;
    const int n0 = ch * 128 + colg * 64;

    // B-frags: col = n0 + 32s + 2*l15 + tt, k = 32c + 8q + j (16B contiguous)
    half8_t bf[2][2][8];
#pragma unroll
    for (int s = 0; s < 2; ++s)
#pragma unroll
        for (int tt = 0; tt < 2; ++tt) {
            const char* bp = (const char*)Ut
                           + (size_t)(n0 + 32 * s + 2 * l15 + tt) * 528 + q * 16;
#pragma unroll
            for (int c = 0; c < 8; ++c)
                bf[s][tt][c] = *(const half8_t*)(bp + c * 64);
        }

    // A-frags: A row l15 <-> t = t0 + 16*rowg + l15; k = 32c + 8q + j
    const float* ap = x + ((size_t)b * 512 + t0 + 16 * rowg + l15) * 256 + 8 * q;
    half8_t af[8];
#pragma unroll
    for (int c = 0; c < 8; ++c) {
        float4 a0 = *(const float4*)(ap + 32 * c);
        float4 a1 = *(const float4*)(ap + 32 * c + 4);
        uint4 u;
        u.x = __builtin_bit_cast(unsigned, pk_h2(a0.x, a0.y));
        u.y = __builtin_bit_cast(unsigned, pk_h2(a0.z, a0.w));
        u.z = __builtin_bit_cast(unsigned, pk_h2(a1.x, a1.y));
        u.w = __builtin_bit_cast(unsigned, pk_h2(a1.z, a1.w));
        af[c] = __builtin_bit_cast(half8_t, u);
    }

    float4_t acc[2][2];
#pragma unroll
    for (int s = 0; s < 2; ++s)
#pragma unroll
        for (int tt = 0; tt < 2; ++tt)
#pragma unroll
            for (int i = 0; i < 4; ++i) acc[s][tt][i] = 0.f;

#pragma unroll
    for (int c = 0; c < 8; ++c)
#pragma unroll
        for (int s = 0; s < 2; ++s)
#pragma unroll
            for (int tt = 0; tt < 2; ++tt)
                acc[s][tt] = MFMA16(af[c], bf[s][tt][c], acc[s][tt]);

    // store: C row 4q+i <-> t = t0+16*rowg+4q+i; half2 idx = n0/2 + 16s + l15
#pragma unroll
    for (int s = 0; s < 2; ++s)
#pragma unroll
        for (int i = 0; i < 4; ++i) {
            half2_t p = pk_h2(acc[s][0][i], acc[s][1][i]);
            xu[(size_t)((t0 + 16 * rowg + 4 * q + i) * 256 + b) * 128
               + (n0 >> 1) + 16 * s + l15] = p;
        }
}

// ---------------- Phase 2: 512-step scan, 8 waves (R2 config) ---------------------
// Wave w owns cols [32w,32w+32) as col-interleaved pair: cols 32w+2*l15+tt.
__global__ __launch_bounds__(512, 2) void rnn_scan(
    const half2_t* __restrict__ xu,     // [(t*256+b)][128] half2
    const float* __restrict__ W,        // [256][256] fp32
    const float* __restrict__ bias,     // [256]
    float* __restrict__ out)            // [256][256] fp32
{
    __shared__ char lds[16896];         // h dbuf: 2 x (16 rows x 528B: 256 f16 + pad)
    const int tid = threadIdx.x;
    const int lane = tid & 63, w = tid >> 6, l15 = lane & 15, q = lane >> 4;
    const int blk = blockIdx.x;
    const int c0 = 32 * w + 2 * l15;

    // W -> B-frags: wf[tt][c], k = 32c+8q+j, col = c0+tt
    half8_t wf[2][8];
#pragma unroll
    for (int tt = 0; tt < 2; ++tt)
#pragma unroll
        for (int c = 0; c < 8; ++c) {
            half8_t f;
#pragma unroll
            for (int j = 0; j < 8; ++j) {
                int k = 32 * c + q * 8 + j;
                f[j] = (_Float16)W[k * 256 + c0 + tt];
            }
            wf[tt][c] = f;
        }
    const float b0 = bias[c0], b1 = bias[c0 + 1];

    // h0 = 0
    for (int i = tid; i < 16896 / 4; i += 512) ((int*)lds)[i] = 0;

    const int rowg0 = 16 * blk + 4 * q;
    const int cp = 16 * w + l15;        // half2 col index

    auto load_xu = [&](half2_t (&dst)[4], int t) {
#pragma unroll
        for (int i = 0; i < 4; ++i)
            dst[i] = xu[((size_t)t * 256 + rowg0 + i) * 128 + cp];
    };

    half2_t xc[4], xn[4];
    load_xu(xc, 0);
    load_xu(xn, 1);
    __syncthreads();    // one-time full drain (h0 zeros visible)

    char* const hbuf0 = (char*)lds;
    char* const hbuf1 = (char*)lds + 8448;

    auto step = [&](half2_t (&xreg)[4], int t) {
        float4_t acc0, acc1;
#pragma unroll
        for (int i = 0; i < 4; ++i) {
            acc0[i] = (float)xreg[i][0];
            acc1[i] = (float)xreg[i][1];
        }

        int tp = t + 2 > 511 ? 511 : t + 2;     // depth-2 prefetch, rides across barrier
        load_xu(xreg, tp);

        const char* hcur = (t & 1) ? hbuf1 : hbuf0;
        half8_t af[8];
#pragma unroll
        for (int c = 0; c < 8; ++c)
            af[c] = *(const half8_t*)(hcur + l15 * 528 + c * 64 + q * 16);

#pragma unroll
        for (int c = 0; c < 8; ++c) {
            acc0 = MFMA16(af[c], wf[0][c], acc0);
            acc1 = MFMA16(af[c], wf[1][c], acc1);
        }

        if (t == 511) {
#pragma unroll
            for (int i = 0; i < 4; ++i) {
                float v0 = fast_tanh(acc0[i] + b0);
                float v1 = fast_tanh(acc1[i] + b1);
                float2 st; st.x = v0; st.y = v1;
                *(float2*)(&out[(rowg0 + i) * 256 + c0]) = st;
            }
        } else {
            char* hnext = ((t + 1) & 1) ? hbuf1 : hbuf0;
#pragma unroll
            for (int i = 0; i < 4; ++i) {
                float v0 = fast_tanh(acc0[i] + b0);
                float v1 = fast_tanh(acc1[i] + b1);
                *(half2_t*)(hnext + (4 * q + i) * 528 + c0 * 2) = pk_h2(v0, v1);
            }
            BARRIER_LGKM();     // LDS-only sync; xu loads stay in flight
        }
    };

    for (int t2 = 0; t2 < 512; t2 += 2) {
        step(xc, t2);
        step(xn, t2 + 1);
    }
}

extern "C" void kernel_launch(void* const* d_in, const int* in_sizes, int n_in,
                              void* d_out, int out_size, void* d_ws, size_t ws_size,
                              hipStream_t stream) {
    const float* x = (const float*)d_in[0];   // [256,512,256]
    const float* U = (const float*)d_in[1];   // [256,256]
    const float* W = (const float*)d_in[2];   // [256,256]
    const float* b = (const float*)d_in[3];   // [256]
    float* out = (float*)d_out;

    char* ws = (char*)d_ws;
    _Float16* Ut = (_Float16*)ws;                       // 135168 B
    half2_t*  xu = (half2_t*)(ws + 262144);             // 67,108,864 B

    transpose_u<<<256, 256, 0, stream>>>(U, Ut);
    xu_gemm<<<8192, 256, 0, stream>>>(x, Ut, xu);
    rnn_scan<<<16, 512, 0, stream>>>(xu, W, b, out);
}

// Round 6
// 573.040 us; speedup vs baseline: 1.3019x; 1.0958x over previous
//
#include <hip/hip_runtime.h>
#include <hip/hip_bf16.h>

// RNN: h_t = tanh(x_t U + h_{t-1} W + b), return h_T.  B=256 T=512 D=K=256.
// Phase 0: transpose U -> Ut fp16 [256][264] (528B rows).
// Phase 1: xu_gemm v5 — LDS-tiled, one K-sweep. Block = (b, 64-t chunk):
//          As = 64x256 fp16 full-K A-tile (32KB, XOR-swizzled, staged once,
//          x read exactly once); Bs = 256x64 B-quarter (32KB, restaged 4x with
//          register prefetch). 8 waves = 2 rowg x 4 colg; 64 MFMA/wave.
//          LDS total 65536 B (m132-proven size).
// Phase 2: scan, R5 config (8 waves, lgkm-only barrier, depth-2 prefetch),
//          branchless (t+2)&511 wrap.

typedef _Float16 half8_t __attribute__((ext_vector_type(8)));
typedef _Float16 half2_t __attribute__((ext_vector_type(2)));
typedef float    float4_t __attribute__((ext_vector_type(4)));

#define MFMA16(a, b, c) __builtin_amdgcn_mfma_f32_16x16x32_f16((a), (b), (c), 0, 0, 0)
#define BARRIER_LGKM() asm volatile("s_waitcnt lgkmcnt(0)\n\ts_barrier" ::: "memory")

__device__ __forceinline__ half2_t pk_h2(float a, float b) {
    auto r = __builtin_amdgcn_cvt_pkrtz(a, b);
    return __builtin_bit_cast(half2_t, r);
}
__device__ __forceinline__ unsigned pk_u(float a, float b) {
    return __builtin_bit_cast(unsigned, pk_h2(a, b));
}

__device__ __forceinline__ float fast_tanh(float x) {
    float e = __expf(2.0f * x);
    return 1.0f - 2.0f * __builtin_amdgcn_rcpf(e + 1.0f);
}

// ---------------- Phase 0 ----------------
__global__ void transpose_u(const float* __restrict__ U, _Float16* __restrict__ Ut) {
    int id = blockIdx.x * 256 + threadIdx.x;
    int d = id >> 8, n = id & 255;
    Ut[n * 264 + d] = (_Float16)U[id];
}

// ---------------- Phase 1: xu GEMM v5 ----------------
// bx = b*8 + tc. Rows t in [64tc, 64tc+64) at fixed b; cols 0..255.
// Wave w: rowg=w&1 (32 rows), colg=w>>1 (64 cols as 2 superpairs x interleave).
__global__ __launch_bounds__(512, 1) void xu_gemm(
    const float* __restrict__ x,        // [256][512][256] fp32
    const _Float16* __restrict__ Ut,    // [256][264] fp16
    half2_t* __restrict__ xu)           // [(t*256+b)][128] half2
{
    __shared__ char As[32768];          // [r(64)][512B], chunk16 ^ (r&7)
    __shared__ char Bs[32768];          // [n(256)][128B], chunk16 ^ ((n>>1)&7)
    const int tid = threadIdx.x;
    const int lane = tid & 63, w = tid >> 6, l15 = lane & 15, q = lane >> 4;
    const int bx = blockIdx.x;
    const int b = bx >> 3, tc = bx & 7;
    const int rowg = w & 1, colg = w >> 1;

    // ---- stage As: 64 rows x 1KB fp32 -> fp16 swizzled (x read once, coalesced)
#pragma unroll
    for (int i = 0; i < 4; ++i) {
        int task = tid + 512 * i;           // r(64) x ch(32)
        int r = task >> 5, ch = task & 31;
        const float* gp = x + ((size_t)b * 512 + 64 * tc + r) * 256 + ch * 8;
        float4 a0 = *(const float4*)gp;
        float4 a1 = *(const float4*)(gp + 4);
        uint4 u;
        u.x = pk_u(a0.x, a0.y);
        u.y = pk_u(a0.z, a0.w);
        u.z = pk_u(a1.x, a1.y);
        u.w = pk_u(a1.z, a1.w);
        *(uint4*)(As + r * 512 + (ch ^ (r & 7)) * 16) = u;
    }

    // ---- Bs quarter staging (L2-resident Ut), register-prefetched
    uint4 breg[4];
    auto loadBq = [&](int qtr) {
#pragma unroll
        for (int i = 0; i < 4; ++i) {
            int task = tid + 512 * i;       // n(256) x ch(8)
            int n = task >> 3, ch = task & 7;
            breg[i] = *(const uint4*)((const char*)Ut + (size_t)n * 528
                                      + qtr * 128 + ch * 16);
        }
    };
    auto writeBq = [&]() {
#pragma unroll
        for (int i = 0; i < 4; ++i) {
            int task = tid + 512 * i;
            int n = task >> 3, ch = task & 7;
            *(uint4*)(Bs + n * 128 + (ch ^ ((n >> 1) & 7)) * 16) = breg[i];
        }
    };

    float4_t acc[2][2][2];                  // [rt][sp][tt]
#pragma unroll
    for (int rt = 0; rt < 2; ++rt)
#pragma unroll
        for (int sp = 0; sp < 2; ++sp)
#pragma unroll
            for (int tt = 0; tt < 2; ++tt)
#pragma unroll
                for (int i = 0; i < 4; ++i) acc[rt][sp][tt][i] = 0.f;

    loadBq(0);
    writeBq();
    __syncthreads();

    for (int qtr = 0; qtr < 4; ++qtr) {
        if (qtr < 3) loadBq(qtr + 1);       // overlap L2 latency with compute
#pragma unroll
        for (int c = 0; c < 2; ++c) {
            half8_t af[2], bf[2][2];
#pragma unroll
            for (int rt = 0; rt < 2; ++rt) {
                int r = 32 * rowg + 16 * rt + l15;
                int ch = qtr * 8 + c * 4 + q;
                af[rt] = *(const half8_t*)(As + r * 512 + (ch ^ (r & 7)) * 16);
            }
#pragma unroll
            for (int sp = 0; sp < 2; ++sp)
#pragma unroll
                for (int tt = 0; tt < 2; ++tt) {
                    int n = 64 * colg + 32 * sp + 2 * l15 + tt;
                    int ch = c * 4 + q;
                    bf[sp][tt] = *(const half8_t*)(Bs + n * 128
                                                   + (ch ^ ((n >> 1) & 7)) * 16);
                }
#pragma unroll
            for (int rt = 0; rt < 2; ++rt)
#pragma unroll
                for (int sp = 0; sp < 2; ++sp)
#pragma unroll
                    for (int tt = 0; tt < 2; ++tt)
                        acc[rt][sp][tt] = MFMA16(af[rt], bf[sp][tt], acc[rt][sp][tt]);
        }
        if (qtr < 3) {
            __syncthreads();                // all Bs reads of this quarter done
            writeBq();
            __syncthreads();                // next quarter visible
        }
    }

    // epilogue: C row 4q+i -> t; cols (tt pair) -> packed half2
#pragma unroll
    for (int rt = 0; rt < 2; ++rt)
#pragma unroll
        for (int sp = 0; sp < 2; ++sp)
#pragma unroll
            for (int i = 0; i < 4; ++i) {
                int t = 64 * tc + 32 * rowg + 16 * rt + 4 * q + i;
                half2_t p = pk_h2(acc[rt][sp][0][i], acc[rt][sp][1][i]);
                xu[((size_t)t * 256 + b) * 128 + 32 * colg + 16 * sp + l15] = p;
            }
}

// ---------------- Phase 2: 512-step scan, 8 waves (R5 config) ---------------------
__global__ __launch_bounds__(512, 2) void rnn_scan(
    const half2_t* __restrict__ xu,     // [(t*256+b)][128] half2
    const float* __restrict__ W,        // [256][256] fp32
    const float* __restrict__ bias,     // [256]
    float* __restrict__ out)            // [256][256] fp32
{
    __shared__ char lds[16896];         // h dbuf: 2 x (16 rows x 528B)
    const int tid = threadIdx.x;
    const int lane = tid & 63, w = tid >> 6, l15 = lane & 15, q = lane >> 4;
    const int blk = blockIdx.x;
    const int c0 = 32 * w + 2 * l15;

    half8_t wf[2][8];
#pragma unroll
    for (int tt = 0; tt < 2; ++tt)
#pragma unroll
        for (int c = 0; c < 8; ++c) {
            half8_t f;
#pragma unroll
            for (int j = 0; j < 8; ++j) {
                int k = 32 * c + q * 8 + j;
                f[j] = (_Float16)W[k * 256 + c0 + tt];
            }
            wf[tt][c] = f;
        }
    const float b0 = bias[c0], b1 = bias[c0 + 1];

    for (int i = tid; i < 16896 / 4; i += 512) ((int*)lds)[i] = 0;

    const int rowg0 = 16 * blk + 4 * q;
    const int cp = 16 * w + l15;

    auto load_xu = [&](half2_t (&dst)[4], int t) {
#pragma unroll
        for (int i = 0; i < 4; ++i)
            dst[i] = xu[((size_t)t * 256 + rowg0 + i) * 128 + cp];
    };

    half2_t xc[4], xn[4];
    load_xu(xc, 0);
    load_xu(xn, 1);
    __syncthreads();

    char* const hbuf0 = (char*)lds;
    char* const hbuf1 = (char*)lds + 8448;

    auto step = [&](half2_t (&xreg)[4], int t) {
        float4_t acc0, acc1;
#pragma unroll
        for (int i = 0; i < 4; ++i) {
            acc0[i] = (float)xreg[i][0];
            acc1[i] = (float)xreg[i][1];
        }

        load_xu(xreg, (t + 2) & 511);   // branchless depth-2 prefetch

        const char* hcur = (t & 1) ? hbuf1 : hbuf0;
        half8_t af[8];
#pragma unroll
        for (int c = 0; c < 8; ++c)
            af[c] = *(const half8_t*)(hcur + l15 * 528 + c * 64 + q * 16);

#pragma unroll
        for (int c = 0; c < 8; ++c) {
            acc0 = MFMA16(af[c], wf[0][c], acc0);
            acc1 = MFMA16(af[c], wf[1][c], acc1);
        }

        if (t == 511) {
#pragma unroll
            for (int i = 0; i < 4; ++i) {
                float v0 = fast_tanh(acc0[i] + b0);
                float v1 = fast_tanh(acc1[i] + b1);
                float2 st; st.x = v0; st.y = v1;
                *(float2*)(&out[(rowg0 + i) * 256 + c0]) = st;
            }
        } else {
            char* hnext = ((t + 1) & 1) ? hbuf1 : hbuf0;
#pragma unroll
            for (int i = 0; i < 4; ++i) {
                float v0 = fast_tanh(acc0[i] + b0);
                float v1 = fast_tanh(acc1[i] + b1);
                *(half2_t*)(hnext + (4 * q + i) * 528 + c0 * 2) = pk_h2(v0, v1);
            }
            BARRIER_LGKM();
        }
    };

    for (int t2 = 0; t2 < 512; t2 += 2) {
        step(xc, t2);
        step(xn, t2 + 1);
    }
}

extern "C" void kernel_launch(void* const* d_in, const int* in_sizes, int n_in,
                              void* d_out, int out_size, void* d_ws, size_t ws_size,
                              hipStream_t stream) {
    const float* x = (const float*)d_in[0];   // [256,512,256]
    const float* U = (const float*)d_in[1];   // [256,256]
    const float* W = (const float*)d_in[2];   // [256,256]
    const float* b = (const float*)d_in[3];   // [256]
    float* out = (float*)d_out;

    char* ws = (char*)d_ws;
    _Float16* Ut = (_Float16*)ws;                       // 135168 B
    half2_t*  xu = (half2_t*)(ws + 262144);             // 67,108,864 B

    transpose_u<<<256, 256, 0, stream>>>(U, Ut);
    xu_gemm<<<2048, 512, 0, stream>>>(x, Ut, xu);
    rnn_scan<<<16, 512, 0, stream>>>(xu, W, b, out);
}